// Round 2
// baseline (17394.504 us; speedup 1.0000x reference)
//
#include <hip/hip_runtime.h>
#include <math.h>

#define B_    16
#define T_    170
#define D_    512
#define H_    8
#define L_    8
#define V_    4672
#define S_    510      // 3*T
#define HD_   64
#define DFF_  2048
#define NTOK  (B_*S_)  // 8160
#define NROW  (B_*T_)  // 2720

// ---------------------------------------------------------------- embed
__global__ __launch_bounds__(128) void embed_kernel(
    const float* __restrict__ states, const int* __restrict__ actions,
    const float* __restrict__ goals, const int* __restrict__ timesteps,
    const float* __restrict__ state_W, const float* __restrict__ state_b,
    const float* __restrict__ act_emb, const float* __restrict__ goal_W,
    const float* __restrict__ goal_b, const float* __restrict__ pos_emb,
    const float* __restrict__ gpos_emb, float* __restrict__ X)
{
    int blk = blockIdx.x;
    int b = blk / S_, s = blk % S_;
    int t = s / 3, type = s % 3;
    int tid = threadIdx.x;
    __shared__ float srow[768];
    if (type == 1) {
        const float* sp = states + ((size_t)(b*T_ + t))*768;
        for (int i = tid; i < 768; i += 128) srow[i] = sp[i];
    }
    __syncthreads();
    int ts = timesteps[b*T_ + t];
    float* xo = X + (size_t)blk * D_;
    for (int d = tid; d < D_; d += 128) {
        float tokv;
        if (type == 0) {
            tokv = tanhf(goals[b*T_ + t] * goal_W[d] + goal_b[d]);
        } else if (type == 1) {
            const float* wr = state_W + (size_t)d * 768;
            float acc = state_b[d];
            for (int i = 0; i < 768; i++) acc += srow[i] * wr[i];
            tokv = acc;
        } else {
            int a = actions[b*T_ + t];
            tokv = tanhf(act_emb[(size_t)a * D_ + d]);
        }
        xo[d] = tokv + gpos_emb[(size_t)ts * D_ + d] + pos_emb[(size_t)s * D_ + d];
    }
}

// ---------------------------------------------------------------- layernorm (one wave per token)
__global__ __launch_bounds__(64) void ln_kernel(
    const float* __restrict__ x, const float* __restrict__ g,
    const float* __restrict__ beta, float* __restrict__ out)
{
    int tok = blockIdx.x;
    int tid = threadIdx.x;
    const float* xr = x + (size_t)tok * D_;
    float e[8];
    float s = 0.f, sq = 0.f;
#pragma unroll
    for (int i = 0; i < 8; i++) {
        e[i] = xr[tid + i*64];
        s += e[i]; sq += e[i]*e[i];
    }
#pragma unroll
    for (int m = 32; m >= 1; m >>= 1) {
        s  += __shfl_xor(s,  m, 64);
        sq += __shfl_xor(sq, m, 64);
    }
    float mean = s * (1.f/D_);
    float var  = sq * (1.f/D_) - mean*mean;
    float inv  = rsqrtf(var + 1e-5f);
    float* o = out + (size_t)tok * D_;
#pragma unroll
    for (int i = 0; i < 8; i++) {
        int c = tid + i*64;
        o[c] = (e[i]-mean)*inv*g[c] + beta[c];
    }
}

// ---------------------------------------------------------------- generic f32 GEMM: C[M,N] = A[M,K] * W[N,K]^T (+bias)(+fuse)
// FUSE: 0 = none, 1 = +res (residual add), 2 = exact gelu
template<int FUSE>
__global__ __launch_bounds__(256) void gemm_kernel(
    const float* __restrict__ A, const float* __restrict__ W,
    const float* __restrict__ bias, const float* __restrict__ res,
    float* __restrict__ C, int M, int N, int K)
{
    __shared__ float As[64][17];
    __shared__ float Ws[64][17];
    int tid = threadIdx.x;
    int tx = tid & 15, ty = tid >> 4;
    int rowBase = blockIdx.y * 64;
    int colBase = blockIdx.x * 64;
    int lr = tid >> 2;
    int lc = (tid & 3) << 2;
    float acc[4][4] = {};
    for (int k0 = 0; k0 < K; k0 += 16) {
        int ar = rowBase + lr;
        float4 av = make_float4(0.f,0.f,0.f,0.f);
        if (ar < M) av = *(const float4*)(A + (size_t)ar*K + k0 + lc);
        As[lr][lc+0]=av.x; As[lr][lc+1]=av.y; As[lr][lc+2]=av.z; As[lr][lc+3]=av.w;
        float4 wv = *(const float4*)(W + (size_t)(colBase+lr)*K + k0 + lc);
        Ws[lr][lc+0]=wv.x; Ws[lr][lc+1]=wv.y; Ws[lr][lc+2]=wv.z; Ws[lr][lc+3]=wv.w;
        __syncthreads();
#pragma unroll
        for (int kk = 0; kk < 16; kk++) {
            float a[4], bb[4];
#pragma unroll
            for (int i = 0; i < 4; i++) a[i] = As[ty*4+i][kk];
#pragma unroll
            for (int j = 0; j < 4; j++) bb[j] = Ws[tx*4+j][kk];
#pragma unroll
            for (int i = 0; i < 4; i++)
#pragma unroll
                for (int j = 0; j < 4; j++)
                    acc[i][j] += a[i]*bb[j];
        }
        __syncthreads();
    }
#pragma unroll
    for (int i = 0; i < 4; i++) {
        int m = rowBase + ty*4 + i;
        if (m >= M) continue;
#pragma unroll
        for (int j = 0; j < 4; j++) {
            int n = colBase + tx*4 + j;
            float v = acc[i][j];
            if (bias) v += bias[n];
            if (FUSE == 1) v += res[(size_t)m*N + n];
            if (FUSE == 2) v = 0.5f*v*(1.f + erff(v*0.70710678118654752f));
            C[(size_t)m*N + n] = v;
        }
    }
}

// ---------------------------------------------------------------- attention: one block per (q-row, b*h)
// NOTE: Y may alias Q. Block (q,bh) is the only reader of Q row (b,q,h*64..),
// reads it into LDS (followed by __syncthreads) before the Y-write at the end.
__global__ __launch_bounds__(128) void attn_kernel(
    const float* __restrict__ Q, const float* __restrict__ K,
    const float* __restrict__ V, float* __restrict__ Y)
{
    int q  = blockIdx.x;
    int bh = blockIdx.y;
    int b = bh >> 3, h = bh & 7;
    int tid = threadIdx.x;
    __shared__ float qv[HD_];
    __shared__ float sc[S_];
    __shared__ float red[128];
    const size_t base = (size_t)b * S_ * D_ + (size_t)h * HD_;
    if (tid < HD_) qv[tid] = Q[base + (size_t)q*D_ + tid];
    __syncthreads();
    int nk = q + 1;
    const float scale = 0.125f;   // 1/sqrt(64)
    for (int j = tid; j < nk; j += 128) {
        const float* kr = K + base + (size_t)j*D_;
        float s = 0.f;
#pragma unroll
        for (int d = 0; d < HD_; d++) s += qv[d]*kr[d];
        sc[j] = s * scale;
    }
    __syncthreads();
    float m = -1e30f;
    for (int j = tid; j < nk; j += 128) m = fmaxf(m, sc[j]);
    red[tid] = m; __syncthreads();
    for (int st = 64; st >= 1; st >>= 1) {
        if (tid < st) red[tid] = fmaxf(red[tid], red[tid+st]);
        __syncthreads();
    }
    m = red[0]; __syncthreads();
    float ps = 0.f;
    for (int j = tid; j < nk; j += 128) {
        float e = expf(sc[j]-m);
        sc[j] = e; ps += e;
    }
    red[tid] = ps; __syncthreads();
    for (int st = 64; st >= 1; st >>= 1) {
        if (tid < st) red[tid] += red[tid+st];
        __syncthreads();
    }
    float inv = 1.f / red[0];
    if (tid < HD_) {
        float acc = 0.f;
        const float* vr = V + base + tid;
        for (int j = 0; j < nk; j++) acc += sc[j] * vr[(size_t)j*D_];
        Y[base + (size_t)q*D_ + tid] = acc * inv;
    }
}

// ---------------------------------------------------------------- gather action-position tokens
__global__ __launch_bounds__(128) void gather_kernel(
    const float* __restrict__ Hn, float* __restrict__ G)
{
    int m = blockIdx.x;
    int b = m / T_, t = m % T_;
    const float* src = Hn + ((size_t)(b*S_ + 3*t + 2))*D_;
    float* dst = G + (size_t)m*D_;
    for (int d = threadIdx.x; d < D_; d += 128) dst[d] = src[d];
}

// ---------------------------------------------------------------- per-row CE loss
__global__ __launch_bounds__(256) void rowloss_kernel(
    const float* __restrict__ logits, const int* __restrict__ targets,
    float* __restrict__ rowl)
{
    int m = blockIdx.x;
    int tid = threadIdx.x;
    const float* row = logits + (size_t)m*V_;
    __shared__ float red[256];
    float mx = -1e30f;
    for (int n = tid; n < V_; n += 256) mx = fmaxf(mx, row[n]);
    red[tid] = mx; __syncthreads();
    for (int st = 128; st >= 1; st >>= 1) {
        if (tid < st) red[tid] = fmaxf(red[tid], red[tid+st]);
        __syncthreads();
    }
    mx = red[0]; __syncthreads();
    float s = 0.f;
    for (int n = tid; n < V_; n += 256) s += expf(row[n]-mx);
    red[tid] = s; __syncthreads();
    for (int st = 128; st >= 1; st >>= 1) {
        if (tid < st) red[tid] += red[tid+st];
        __syncthreads();
    }
    if (tid == 0) {
        float lse = mx + logf(red[0]);
        rowl[m] = lse - row[targets[m]];
    }
}

__global__ __launch_bounds__(256) void finalloss_kernel(
    const float* __restrict__ rowl, float* __restrict__ out)
{
    int tid = threadIdx.x;
    __shared__ float red[256];
    float s = 0.f;
    for (int i = tid; i < NROW; i += 256) s += rowl[i];
    red[tid] = s; __syncthreads();
    for (int st = 128; st >= 1; st >>= 1) {
        if (tid < st) red[tid] += red[tid+st];
        __syncthreads();
    }
    if (tid == 0) out[0] = red[0] * (1.f/NROW);
}

// Fallback sentinel: keeps the captured graph non-empty and marks the
// "workspace too small" diagnostic in d_out[0].
__global__ void sentinel_kernel(float* out) {
    if (threadIdx.x == 0 && blockIdx.x == 0) out[0] = -12345.0f;
}

// ---------------------------------------------------------------- launch
extern "C" void kernel_launch(void* const* d_in, const int* in_sizes, int n_in,
                              void* d_out, int out_size, void* d_ws, size_t ws_size,
                              hipStream_t stream)
{
    const float* states    = (const float*)d_in[0];
    const int*   actions   = (const int*)  d_in[1];
    const float* goals     = (const float*)d_in[2];
    const int*   timesteps = (const int*)  d_in[3];
    const int*   targets   = (const int*)  d_in[4];
    const float* state_W   = (const float*)d_in[5];
    const float* state_b   = (const float*)d_in[6];
    const float* act_emb   = (const float*)d_in[7];
    const float* goal_W    = (const float*)d_in[8];
    const float* goal_b    = (const float*)d_in[9];
    const float* pos_emb   = (const float*)d_in[10];
    const float* gpos_emb  = (const float*)d_in[11];
    const float* ln1_g     = (const float*)d_in[12];
    const float* ln1_b     = (const float*)d_in[13];
    const float* Wq        = (const float*)d_in[14];
    const float* bq        = (const float*)d_in[15];
    const float* Wk        = (const float*)d_in[16];
    const float* bk        = (const float*)d_in[17];
    const float* Wv        = (const float*)d_in[18];
    const float* bv        = (const float*)d_in[19];
    const float* Wp        = (const float*)d_in[20];
    const float* bp        = (const float*)d_in[21];
    const float* ln2_g     = (const float*)d_in[22];
    const float* ln2_b     = (const float*)d_in[23];
    const float* W1        = (const float*)d_in[24];
    const float* b1        = (const float*)d_in[25];
    const float* W2        = (const float*)d_in[26];
    const float* b2        = (const float*)d_in[27];
    const float* lnf_g     = (const float*)d_in[28];
    const float* lnf_b     = (const float*)d_in[29];
    const float* head_W    = (const float*)d_in[30];

    const size_t nX = (size_t)NTOK * D_;           // 4,177,920 floats
    // Total workspace: exactly 5*nX floats = 83.6 MB.
    if (ws_size < 5 * nX * sizeof(float)) {
        sentinel_kernel<<<1, 64, 0, stream>>>((float*)d_out);
        return;
    }

    float* ws = (float*)d_ws;
    float* X    = ws;           // residual stream
    float* Hb   = X  + nX;      // LN output
    float* Qb   = Hb + nX;      // Q; aliased: Y (attn out), GATH (final gather)
    float* Kb   = Qb + nX;      // K; aliased: HID chunk (MLP), ROWL (loss)
    float* Vb   = Kb + nX;      // V; aliased: HID chunk (MLP, upper half)
    float* Yb   = Qb;           // alias (see attn_kernel note)
    float* HID  = Kb;           // alias: K,V dead during MLP; 2*nX floats = 4080 rows of DFF
    float* GATH = Qb;           // alias: Q/Y dead after last layer
    float* ROWL = Kb;           // alias
    float* logits = (float*)d_out;

    embed_kernel<<<NTOK, 128, 0, stream>>>(states, actions, goals, timesteps,
        state_W, state_b, act_emb, goal_W, goal_b, pos_emb, gpos_emb, X);

    const int CH = 4080;             // MLP row-chunk: 2*nX/DFF = 4080 rows
    dim3 gD(D_/64,   (NTOK+63)/64);  // (8, 128)
    dim3 gDc(D_/64,  (CH+63)/64);    // (8, 64)
    dim3 gFc(DFF_/64,(CH+63)/64);    // (32, 64)
    for (int l = 0; l < L_; l++) {
        size_t wOff  = (size_t)l * D_ * D_;
        size_t fOff  = (size_t)l * DFF_ * D_;
        ln_kernel<<<NTOK, 64, 0, stream>>>(X, ln1_g + l*D_, ln1_b + l*D_, Hb);
        gemm_kernel<0><<<gD, 256, 0, stream>>>(Hb, Wq + wOff, bq + l*D_, nullptr, Qb, NTOK, D_, D_);
        gemm_kernel<0><<<gD, 256, 0, stream>>>(Hb, Wk + wOff, bk + l*D_, nullptr, Kb, NTOK, D_, D_);
        gemm_kernel<0><<<gD, 256, 0, stream>>>(Hb, Wv + wOff, bv + l*D_, nullptr, Vb, NTOK, D_, D_);
        attn_kernel<<<dim3(S_, B_*H_), 128, 0, stream>>>(Qb, Kb, Vb, Yb);
        gemm_kernel<1><<<gD, 256, 0, stream>>>(Yb, Wp + wOff, bp + l*D_, X, X, NTOK, D_, D_);
        ln_kernel<<<NTOK, 64, 0, stream>>>(X, ln2_g + l*D_, ln2_b + l*D_, Hb);
        // MLP in 2 row-chunks so HID fits in the (dead) K+V region.
        for (int r0 = 0; r0 < NTOK; r0 += CH) {
            gemm_kernel<2><<<gFc, 256, 0, stream>>>(Hb + (size_t)r0*D_, W1 + fOff, b1 + l*DFF_,
                                                    nullptr, HID, CH, DFF_, D_);
            gemm_kernel<1><<<gDc, 256, 0, stream>>>(HID, W2 + fOff, b2 + l*D_,
                                                    X + (size_t)r0*D_, X + (size_t)r0*D_, CH, D_, DFF_);
        }
    }
    ln_kernel<<<NTOK, 64, 0, stream>>>(X, lnf_g, lnf_b, Hb);
    gather_kernel<<<NROW, 128, 0, stream>>>(Hb, GATH);
    dim3 gH(V_/64, (NROW+63)/64);    // (73, 43)
    gemm_kernel<0><<<gH, 256, 0, stream>>>(GATH, head_W, nullptr, nullptr, logits, NROW, V_, D_);
    rowloss_kernel<<<NROW, 256, 0, stream>>>(logits, targets, ROWL);
    finalloss_kernel<<<1, 256, 0, stream>>>(ROWL, logits + (size_t)NROW * V_);
}